// Round 4
// baseline (82.369 us; speedup 1.0000x reference)
//
#include <hip/hip_runtime.h>
#include <math.h>

// SnakeLoss: x,target [B=64, N=1024, 2] fp32.
// shift_means[b,s] = (1/N) sum_j ||x[b,j] - target[b,(j-s)%N]||
// out = mean_b min_s shift_means[b,s]   (scalar fp32)
//
// V4: dispatch-count reduction. The timed window is dominated by the fixed
// 40 us ws-poison fill + dispatch gaps; compute (~8 us) is no longer the
// lever. Fuse min+final into one kernel (block-min per batch, atomicAdd of
// the scaled contribution into out[0]); out[0] is zeroed by the partial
// kernel (prior dispatch, same stream -> ordered). 3 dispatches -> 2.
// snake_partial unchanged from V3 (t shared across G=4 shifts, one
// ds_read_b128 feeds 8 distances; x on the scalar/SMEM path; raw v_sqrt_f32).

#define BATCH 64
#define NPT   1024
#define TPB   256
#define G     4              // shifts per thread (s = tid + 256g)
#define JGRP  16             // j chunks -> grid = 64*16 = 1024 blocks
#define JLEN  (NPT / JGRP)   // 64
#define TWIN  (JLEN + 256)   // 320 window entries (need 319)

__global__ __launch_bounds__(TPB) void snake_partial(
    const float2* __restrict__ x, const float2* __restrict__ tgt,
    float* __restrict__ partial, float* __restrict__ out) {
  const int b   = blockIdx.x;
  const int jg  = blockIdx.y;
  const int tid = threadIdx.x;
  const int j0  = jg * JLEN;

  // zero the atomic target for the next kernel (no extra memset dispatch)
  if (b == 0 && jg == 0 && tid == 0) out[0] = 0.f;

  // t4[w] = (t[(kb+w)%N], t[(kb+w+1)%N]), kb = j0-255: one b128 = 2 t-values.
  __shared__ float4 t4[TWIN];
  const float2* tb = tgt + b * NPT;
  const int kb = (j0 - 255) & (NPT - 1);
  for (int w = tid; w < TWIN; w += TPB) {
    const float2 a = tb[(kb + w) & (NPT - 1)];
    const float2 c = tb[(kb + w + 1) & (NPT - 1)];
    t4[w] = make_float4(a.x, a.y, c.x, c.y);
  }
  __syncthreads();

  // x chunk base per group: cg = (j0 + 256g) % N; chunks never wrap (64-long,
  // 64-aligned). Uniform addresses -> scalar loads, no LDS/VMEM-lane traffic.
  const float4* xg[G];
#pragma unroll
  for (int g = 0; g < G; ++g) {
    const int cg = (j0 + 256 * g) & (NPT - 1);
    xg[g] = (const float4*)(x + b * NPT + cg);
  }

  float2 acc[G];
#pragma unroll
  for (int g = 0; g < G; ++g) acc[g] = make_float2(0.f, 0.f);

  const int off0 = 255 - tid;  // t4[off0+jl] = (t[j0+jl-tid], t[j0+jl+1-tid])
#pragma unroll 4
  for (int jl = 0; jl < JLEN; jl += 2) {
    const float4 tp = t4[off0 + jl];  // shared by all 4 shift groups
#pragma unroll
    for (int g = 0; g < G; ++g) {
      const float4 xp = xg[g][jl >> 1];  // uniform: s_load_dwordx4
      const float dx0 = xp.x - tp.x, dy0 = xp.y - tp.y;
      const float dx1 = xp.z - tp.z, dy1 = xp.w - tp.w;
      acc[g].x += __builtin_amdgcn_sqrtf(fmaf(dx0, dx0, dy0 * dy0));
      acc[g].y += __builtin_amdgcn_sqrtf(fmaf(dx1, dx1, dy1 * dy1));
    }
  }

  float* prow = partial + (jg * BATCH + b) * NPT;  // s innermost: coalesced
#pragma unroll
  for (int g = 0; g < G; ++g)
    prow[tid + 256 * g] = acc[g].x + acc[g].y;
}

// grid BATCH: thread handles 4 shifts; sum 16 jg-partials per shift, block-min
// over all 1024 shifts, then one atomicAdd of the scaled min into out[0].
__global__ __launch_bounds__(TPB) void snake_min_final(
    const float* __restrict__ partial, float* __restrict__ out) {
  const int b   = blockIdx.x;
  const int tid = threadIdx.x;
  float m = 3.4e38f;
#pragma unroll
  for (int si = 0; si < NPT / TPB; ++si) {
    const int s = si * TPB + tid;
    float tot = 0.f;
#pragma unroll
    for (int jg = 0; jg < JGRP; ++jg)
      tot += partial[(jg * BATCH + b) * NPT + s];
    m = fminf(m, tot);
  }
  for (int o = 32; o > 0; o >>= 1)
    m = fminf(m, __shfl_down(m, o));
  __shared__ float red[4];
  if ((tid & 63) == 0) red[tid >> 6] = m;
  __syncthreads();
  if (tid == 0) {
    const float bm = fminf(fminf(red[0], red[1]), fminf(red[2], red[3]));
    atomicAdd(out, bm * (1.0f / ((float)NPT * (float)BATCH)));
  }
}

extern "C" void kernel_launch(void* const* d_in, const int* in_sizes, int n_in,
                              void* d_out, int out_size, void* d_ws, size_t ws_size,
                              hipStream_t stream) {
  const float2* x   = (const float2*)d_in[0];
  const float2* tgt = (const float2*)d_in[1];
  float* partial = (float*)d_ws;   // 16*64*1024 floats = 4 MB
  float* out     = (float*)d_out;

  dim3 g1(BATCH, JGRP);
  snake_partial<<<g1, TPB, 0, stream>>>(x, tgt, partial, out);
  snake_min_final<<<BATCH, TPB, 0, stream>>>(partial, out);
}